// Round 6
// baseline (814.292 us; speedup 1.0000x reference)
//
#include <hip/hip_runtime.h>
#include <math.h>

#define Bb 128
#define Tt 1024
#define Ll 96

typedef float v4f __attribute__((ext_vector_type(4)));
typedef _Float16 v2h __attribute__((ext_vector_type(2)));

// One block per batch, ONE wave, no barriers. Lane owns cols c0=tid and
// c1=64+(tid&31) (dup on lanes 32..63). E = exp(trans) as 96 packed-f16 half2
// VGPRs/lane; matvec via v_dot2_f32_f16 (f32 accum). p in LDS as f16.
// Predictive normalizer (R5 post-mortem: stale 1-step normalizer is an
// undamped oscillator -> f16 overflow/NaN). With L_t = log sum Praw_t:
//   d_t = L_{t-1} - d_{t-1} + (L_{t-1} - L_{t-2} + d_{t-2})
// gives log sum p_t = g_t - g_{t-1} EXACTLY (no recursive mode) -> f16-safe.
// x prefetch: 8-slot arrays + #pragma unroll 8 so each load is consumed 8
// iterations after issue (R1-R5: rotation movs forced an in-iteration
// vmcnt drain on HBM-latency loads -> the flat ~1100-1500 cyc/step).

#define REP48(M) M(0) M(1) M(2) M(3) M(4) M(5) M(6) M(7) M(8) M(9) M(10) M(11) \
  M(12) M(13) M(14) M(15) M(16) M(17) M(18) M(19) M(20) M(21) M(22) M(23) \
  M(24) M(25) M(26) M(27) M(28) M(29) M(30) M(31) M(32) M(33) M(34) M(35) \
  M(36) M(37) M(38) M(39) M(40) M(41) M(42) M(43) M(44) M(45) M(46) M(47)

__global__ __launch_bounds__(64) __attribute__((amdgpu_waves_per_eu(1, 1)))
void crf_fwd_kernel(
    const float* __restrict__ inputs,      // (B, T, L) fp32
    const int*   __restrict__ labels_idx,  // (B, T) int32
    const float* __restrict__ trans,       // (L, L) fp32
    float*       __restrict__ out)         // (B, 1) fp32
{
    const int b   = blockIdx.x;
    const int tid = threadIdx.x;          // 0..63
    const int c0  = tid;
    const int c1  = 64 + (tid & 31);
    const bool w1 = (tid < 32);

    __shared__ __align__(16) _Float16 p[Ll];

    const float* xbase = inputs + (size_t)b * Tt * Ll;

    // ---- E in explicit packed-f16 registers (48 half2 per column) ----
#define DECL0(k) v2h E0_##k;
#define DECL1(k) v2h E1_##k;
    REP48(DECL0)
    REP48(DECL1)
#define INIT0(k) { const float* tr = trans + (size_t)(2 * (k)) * Ll; \
    E0_##k = (v2h){(_Float16)__expf(tr[c0]), (_Float16)__expf(tr[Ll + c0])}; }
#define INIT1(k) { const float* tr = trans + (size_t)(2 * (k)) * Ll; \
    E1_##k = (v2h){(_Float16)__expf(tr[c1]), (_Float16)__expf(tr[Ll + c1])}; }
    REP48(INIT0)
    REP48(INIT1)

    // ---- point_score + trans_score (off critical path, once) ----
    float score;
    {
        float psum = 0.f;
        const int* lbl = labels_idx + b * Tt;
        for (int t = tid; t < Tt; t += 64) {
            int i0 = lbl[t];
            psum += xbase[t * Ll + i0];
            if (t < Tt - 1) psum += trans[i0 * Ll + lbl[t + 1]];
        }
        #pragma unroll
        for (int off = 32; off; off >>= 1) psum += __shfl_xor(psum, off, 64);
        score = psum;
    }

    // ---- init: p_0 = exp(state_0) (C_0 = 0); seed normalizer history ----
    float pa0 = __expf(xbase[c0]);
    float pb0 = __expf(xbase[c1]);
    p[c0] = (_Float16)pa0;
    if (w1) p[c1] = (_Float16)pb0;
    float s0 = pa0 + (w1 ? pb0 : 0.f);
    #pragma unroll
    for (int off = 32; off; off >>= 1) s0 += __shfl_xor(s0, off, 64);
    float Lprev = __logf(s0);          // L_0
    float dprev = 0.f;                 // d_0
    float dcur  = Lprev;               // d_1 = L_0
    float inv   = __expf(-dcur);
    float c     = 0.f;

    // ---- x prefetch: 8 slots, consumed 8 iterations after issue ----
    float xA[8], xB[8];
    #pragma unroll
    for (int r = 1; r <= 8; ++r) {
        xA[r & 7] = xbase[r * Ll + c0];
        xB[r & 7] = xbase[r * Ll + c1];
    }

    float pA = 0.f, pB = 0.f;

    #pragma unroll 8
    for (int t = 1; t < Tt; ++t) {
        const int sl = t & 7;          // constant per unrolled body
        float xvA = xA[sl];            // row t (loaded 8 iters ago)
        float xvB = xB[sl];
        int tp = t + 8; if (tp > Tt - 1) tp = Tt - 1;
        const float* xr = xbase + (size_t)tp * Ll;
        xA[sl] = xr[c0];               // load lands directly in slot reg
        xB[sl] = xr[c1];

        float XA = __expf(xvA), XB = __expf(xvB);

        // ---- matvec: 96 v_dot2_f32_f16 (f32 accum), p broadcast from LDS ----
        float aA0 = 0.f, aA1 = 0.f, aA2 = 0.f, aA3 = 0.f;
        float aB0 = 0.f, aB1 = 0.f, aB2 = 0.f, aB3 = 0.f;
#define DOTBLK(i, k0, k1, k2, k3) { \
        v4f q = *reinterpret_cast<const v4f*>(&p[8 * (i)]); \
        v2h h0 = __builtin_bit_cast(v2h, q.x); \
        v2h h1 = __builtin_bit_cast(v2h, q.y); \
        v2h h2 = __builtin_bit_cast(v2h, q.z); \
        v2h h3 = __builtin_bit_cast(v2h, q.w); \
        aA0 = __builtin_amdgcn_fdot2(h0, E0_##k0, aA0, false); \
        aA1 = __builtin_amdgcn_fdot2(h1, E0_##k1, aA1, false); \
        aA2 = __builtin_amdgcn_fdot2(h2, E0_##k2, aA2, false); \
        aA3 = __builtin_amdgcn_fdot2(h3, E0_##k3, aA3, false); \
        aB0 = __builtin_amdgcn_fdot2(h0, E1_##k0, aB0, false); \
        aB1 = __builtin_amdgcn_fdot2(h1, E1_##k1, aB1, false); \
        aB2 = __builtin_amdgcn_fdot2(h2, E1_##k2, aB2, false); \
        aB3 = __builtin_amdgcn_fdot2(h3, E1_##k3, aB3, false); }
        DOTBLK(0,  0, 1, 2, 3)
        DOTBLK(1,  4, 5, 6, 7)
        DOTBLK(2,  8, 9,10,11)
        DOTBLK(3, 12,13,14,15)
        DOTBLK(4, 16,17,18,19)
        DOTBLK(5, 20,21,22,23)
        DOTBLK(6, 24,25,26,27)
        DOTBLK(7, 28,29,30,31)
        DOTBLK(8, 32,33,34,35)
        DOTBLK(9, 36,37,38,39)
        DOTBLK(10,40,41,42,43)
        DOTBLK(11,44,45,46,47)

        float totA = (aA0 + aA1) + (aA2 + aA3);
        float totB = (aB0 + aB1) + (aB2 + aB3);

        float PrA = totA * XA;         // Praw_t = exp(state_t - C_{t-1})
        float PrB = totB * XB;
        pA = fminf(PrA * inv, 60000.f);
        pB = fminf(PrB * inv, 60000.f);
        p[c0] = (_Float16)pA;          // same-wave LDS ordering: no barrier
        if (w1) p[c1] = (_Float16)pB;

        // ---- off-chain (one-iteration slack): L_t reduce + predictive d ----
        float s = PrA + (w1 ? PrB : 0.f);
        #pragma unroll
        for (int off = 32; off; off >>= 1) s += __shfl_xor(s, off, 64);
        float Lcur = __logf(s);        // L_t
        c += dcur;                     // C_t = C_{t-1} + d_t
        float dnext = Lcur - dcur + (Lcur - Lprev + dprev);  // d_{t+1}
        dprev = dcur; dcur = dnext; Lprev = Lcur;
        inv = __expf(-dnext);
    }

    // ---- logZ = log(sum_m p[m]) + C ----
    float e = pA + (w1 ? pB : 0.f);
    #pragma unroll
    for (int off = 32; off; off >>= 1) e += __shfl_xor(e, off, 64);

    if (tid == 0) {
        out[b] = __logf(e) + c - score;
    }
}

extern "C" void kernel_launch(void* const* d_in, const int* in_sizes, int n_in,
                              void* d_out, int out_size, void* d_ws, size_t ws_size,
                              hipStream_t stream) {
    const float* inputs     = (const float*)d_in[0];
    const int*   labels_idx = (const int*)d_in[1];
    const float* trans      = (const float*)d_in[2];
    float*       out        = (float*)d_out;

    crf_fwd_kernel<<<dim3(Bb), dim3(64), 0, stream>>>(inputs, labels_idx, trans, out);
}